// Round 11
// baseline (93.177 us; speedup 1.0000x reference)
//
#include <hip/hip_runtime.h>
#include <hip/hip_cooperative_groups.h>
#include <math.h>

#define B     8
#define C     1024
#define M     8
#define HW    4096
#define EPS   1e-6f
#define GAIN  0.3f

#define TPB   512        // 8 waves
#define TILE  128        // hw per block = 64 float2 slots per wave
#define NTILE 32         // HW/TILE; grid = B*NTILE = 256 (1 block/CU, proven coop size)
#define NG    8          // channel groups = waves (wave-uniform!)
#define CPG   128        // channels per group

typedef float floatx2 __attribute__((ext_vector_type(2)));

// ws: [256][2] stat partials (su, sq) = 2 KB
__global__ __launch_bounds__(TPB, 2) void fused(const float* __restrict__ z,
                                                const float* __restrict__ Wd,
                                                float* __restrict__ out,
                                                float* __restrict__ ws) {
    // LDS: 32 + 4 + 4 KB + eps = ~40.3 KB
    __shared__ __align__(16) float2 scr[NG][M][64];   // cross-wave yz exchange
    __shared__ __align__(16) float2 yzacc[M][64];     // block's reduced yz
    __shared__ float sred[2 * TPB];                   // stats tree
    __shared__ float sh_s[M];
    __shared__ float sh_ms[2];

    const int tid  = threadIdx.x;
    const int bid  = blockIdx.x;
    const int b    = bid >> 5;                 // batch
    const int t    = bid & 31;                 // hw tile
    const int lane = tid & 63;
    // wave id, forced into SGPR so all W indexing is wave-uniform -> s_load
    const int wvu  = __builtin_amdgcn_readfirstlane(tid >> 6);
    const int c0   = wvu * CPG;
    const size_t zoff = ((size_t)(b * C + c0)) * HW + t * TILE + lane * 2;

    // ---------------- phase A: read z once -> stats + in-block yz ----------
    float2 ym[M];
#pragma unroll
    for (int m = 0; m < M; ++m) ym[m] = make_float2(0.f, 0.f);
    float su = 0.f, sq = 0.f;

#pragma unroll 8
    for (int ci = 0; ci < CPG; ++ci) {
        float2 v = *reinterpret_cast<const float2*>(z + zoff + (size_t)ci * HW);
        su += v.x + v.y;
        sq += v.x * v.x + v.y * v.y;
#pragma unroll
        for (int m = 0; m < M; ++m) {
            float w = Wd[m * C + c0 + ci];         // wave-uniform -> s_load
            ym[m].x += w * v.x;
            ym[m].y += w * v.y;
        }
    }

#pragma unroll
    for (int m = 0; m < M; ++m) scr[wvu][m][lane] = ym[m];
    sred[tid] = su;
    sred[TPB + tid] = sq;
    __syncthreads();

    // cross-wave yz reduce: wave wvu owns m = wvu, lane owns its slot
    {
        float2 a = make_float2(0.f, 0.f);
#pragma unroll
        for (int g = 0; g < NG; ++g) {
            float2 v = scr[g][wvu][lane];
            a.x += v.x; a.y += v.y;
        }
        yzacc[wvu][lane] = a;
    }
    // stats block tree-reduce -> ws[bid]
    for (int r = TPB / 2; r > 0; r >>= 1) {
        if (tid < r) {
            sred[tid] += sred[tid + r];
            sred[TPB + tid] += sred[TPB + tid + r];
        }
        __syncthreads();
    }
    if (tid == 0) {
        ws[bid * 2]     = sred[0];
        ws[bid * 2 + 1] = sred[TPB];
    }

    cooperative_groups::this_grid().sync();

    // ---------------- finalize scalars ------------------------------------
    {
        // every wave: s[m = wvu] = sum_c W[wvu, c]
        float sm = 0.f;
#pragma unroll
        for (int k = 0; k < C / 64; ++k) sm += Wd[wvu * C + k * 64 + lane];
#pragma unroll
        for (int o = 32; o > 0; o >>= 1) sm += __shfl_down(sm, o);
        if (lane == 0) sh_s[wvu] = sm;
        // wave 0 additionally: mu/istd for batch b from 32 block partials
        if (wvu == 0) {
            float pu = 0.f, pq = 0.f;
            if (lane < 32) {
                pu = ws[(b * 32 + lane) * 2];
                pq = ws[(b * 32 + lane) * 2 + 1];
            }
#pragma unroll
            for (int o = 16; o > 0; o >>= 1) {
                pu += __shfl_down(pu, o);
                pq += __shfl_down(pq, o);
            }
            if (lane == 0) {
                const float invN = 1.0f / (float)(C * HW);
                float mu  = pu * invN;
                float var = pq * invN - mu * mu;
                sh_ms[0] = mu;
                sh_ms[1] = 1.0f / sqrtf(var + EPS);
            }
        }
    }
    __syncthreads();
    const float mu = sh_ms[0], istd = sh_ms[1];

    float2 y2[M];
#pragma unroll
    for (int m = 0; m < M; ++m) {
        float2 a  = yzacc[m][lane];
        float off = mu * sh_s[m];
        y2[m].x = istd * (a.x - off);
        y2[m].y = istd * (a.y - off);
    }

    // ---------------- phase B: out = z + GAIN * W^T y (z from L3) ----------
#pragma unroll 8
    for (int ci = CPG - 1; ci >= 0; --ci) {
        float2 v = *reinterpret_cast<const float2*>(z + zoff + (size_t)ci * HW);
        float rx = 0.f, ry = 0.f;
#pragma unroll
        for (int m = 0; m < M; ++m) {
            float w = Wd[m * C + c0 + ci];         // wave-uniform -> s_load
            rx += w * y2[m].x;
            ry += w * y2[m].y;
        }
        floatx2 o;
        o.x = v.x + GAIN * rx;
        o.y = v.y + GAIN * ry;
        __builtin_nontemporal_store(o, reinterpret_cast<floatx2*>(out + zoff + (size_t)ci * HW));
    }
}

extern "C" void kernel_launch(void* const* d_in, const int* in_sizes, int n_in,
                              void* d_out, int out_size, void* d_ws, size_t ws_size,
                              hipStream_t stream) {
    const float* z  = (const float*)d_in[0];   // (8,1024,64,64) fp32
    const float* Wd = (const float*)d_in[1];   // (8,1024) fp32
    float* out = (float*)d_out;
    float* ws  = (float*)d_ws;                 // 2 KB stat partials

    void* args[] = { (void*)&z, (void*)&Wd, (void*)&out, (void*)&ws };
    hipLaunchCooperativeKernel((const void*)fused, dim3(B * NTILE), dim3(TPB),
                               args, 0, stream);
}

// Round 12
// 70.923 us; speedup vs baseline: 1.3138x; 1.3138x over previous
//
#include <hip/hip_runtime.h>
#include <math.h>

#define B    8
#define C    1024
#define M    8
#define HW   4096
#define EPS  1e-6f
#define GAIN 0.3f

typedef float floatx4 __attribute__((ext_vector_type(4)));

// ws layout (float offsets)
#define OFF_YZW   0                          // [B][M][HW] fully-reduced unnormalized yz
#define OFF_STATP (OFF_YZW + B*M*HW)         // [512][2]
#define OFF_S     (OFF_STATP + 512*2)        // [M]

// ---------------- K1: full-C blocks -> stats partials + reduced yz ---------
// grid 512 = B*64 hw-tiles (64 hw each), TPB 512, 2 blocks/CU (16 waves/CU).
// threads: g = tid>>4 (32 ch-groups x 32 ch), s = tid&15 (16 float4 hw slots).
__global__ __launch_bounds__(512, 4) void k1_stats_yz(const float* __restrict__ z,
                                                      const float* __restrict__ Wd,
                                                      float* __restrict__ ws) {
    // W transposed + rotated: Wl[c][(m + (c>>5)) & 7] = W[m][c].
    // Read at (c, m): 4 groups in a wave -> 4 distinct banks (conflict-free).
    __shared__ float Wl[C][M];                        // 32 KB
    __shared__ __align__(16) float4 scr[32][M][16];   // 16 KB cross-group yz
    __shared__ float sred[1024];                      // 4 KB stats tree

    const int tid = threadIdx.x;
    const int bid = blockIdx.x;
    const int b   = bid >> 6;
    const int t   = bid & 63;
    const int g   = tid >> 4;
    const int s   = tid & 15;

    // coalesced W read, transposed-rotated LDS write
#pragma unroll
    for (int k = 0; k < 16; ++k) {
        int idx = k * 512 + tid;           // flat m*C + c
        int m = idx >> 10, c = idx & 1023;
        Wl[c][(m + (c >> 5)) & 7] = Wd[idx];
    }
    __syncthreads();

    float4 ym[M];
#pragma unroll
    for (int m = 0; m < M; ++m) ym[m] = make_float4(0.f, 0.f, 0.f, 0.f);
    float su = 0.f, sq = 0.f;

    const size_t zoff = ((size_t)(b * C + g * 32)) * HW + t * 64 + s * 4;
#pragma unroll 8
    for (int ci = 0; ci < 32; ++ci) {
        float4 v = *reinterpret_cast<const float4*>(z + zoff + (size_t)ci * HW);
        su += (v.x + v.y) + (v.z + v.w);
        sq += v.x * v.x + v.y * v.y + v.z * v.z + v.w * v.w;
        const int c = g * 32 + ci;
        const float* wc = &Wl[c][0];
        const int rot = (c >> 5) & 7;      // == g&7 here, runtime LDS offset is fine
#pragma unroll
        for (int m = 0; m < M; ++m) {      // ym index STATIC (no scratch)
            float w = wc[(m + rot) & 7];
            ym[m].x += w * v.x; ym[m].y += w * v.y;
            ym[m].z += w * v.z; ym[m].w += w * v.w;
        }
    }

#pragma unroll
    for (int m = 0; m < M; ++m) scr[g][m][s] = ym[m];
    sred[tid]       = su;
    sred[512 + tid] = sq;
    __syncthreads();

    // cross-group yz reduce: 128 threads, (m, slot) each sums 32 groups
    if (tid < 128) {
        const int m2 = tid >> 4, s2 = tid & 15;
        float4 a = make_float4(0.f, 0.f, 0.f, 0.f);
#pragma unroll
        for (int g2 = 0; g2 < 32; ++g2) {
            float4 p = scr[g2][m2][s2];
            a.x += p.x; a.y += p.y; a.z += p.z; a.w += p.w;
        }
        *reinterpret_cast<float4*>(ws + OFF_YZW +
            ((size_t)(b * M + m2)) * HW + t * 64 + s2 * 4) = a;
    }
    // block 0: s[m] = sum_c W[m,c] from LDS copy
    if (bid == 0 && tid < 64) {
        const int m = tid >> 3, k = tid & 7;
        float p = 0.f;
        for (int j = 0; j < 128; ++j) {
            int c = k * 128 + j;
            p += Wl[c][(m + (c >> 5)) & 7];
        }
        p += __shfl_down(p, 4);
        p += __shfl_down(p, 2);
        p += __shfl_down(p, 1);
        if (k == 0) ws[OFF_S + m] = p;
    }
    // stats tree -> statp[bid]
    for (int r = 256; r > 0; r >>= 1) {
        if (tid < r) {
            sred[tid]       += sred[tid + r];
            sred[512 + tid] += sred[512 + tid + r];
        }
        __syncthreads();
    }
    if (tid == 0) {
        ws[OFF_STATP + bid * 2]     = sred[0];
        ws[OFF_STATP + bid * 2 + 1] = sred[512];
    }
}

// ---------------- K3: finalize scalars in-block, out = z + GAIN*W^T y ------
// grid 1024 (reversed order), TPB 256, 4 blocks/CU (16 waves/CU).
__global__ __launch_bounds__(256, 4) void k3_apply(const float* __restrict__ z,
                                                   const float* __restrict__ Wd,
                                                   const float* __restrict__ ws,
                                                   float* __restrict__ out) {
    __shared__ float sh[2];
    const int tid  = threadIdx.x;
    const int rbid = 1023 - blockIdx.x;    // reverse: touch K1's freshest z first
    const int nc   = rbid & 15;
    const int t    = (rbid >> 4) & 7;
    const int b    = rbid >> 7;
    const int h    = tid >> 7;             // wave-uniform (waves 0,1 -> 0; 2,3 -> 1)
    const int sl   = tid & 127;
    const int c0   = nc * 64 + h * 32;
    const int hw   = t * 512 + sl * 4;

    // wave 0: mu/istd from 64 stat partials of batch b
    if (tid < 64) {
        const float* sp = ws + OFF_STATP + (size_t)(b * 64 + tid) * 2;
        float su = sp[0], sq = sp[1];
#pragma unroll
        for (int o = 32; o > 0; o >>= 1) {
            su += __shfl_down(su, o);
            sq += __shfl_down(sq, o);
        }
        if (tid == 0) {
            const float invN = 1.0f / (float)(C * HW);
            float mu  = su * invN;
            float var = sq * invN - mu * mu;
            sh[0] = mu;
            sh[1] = 1.0f / sqrtf(var + EPS);
        }
    }
    // overlap: scalar s[m] + raw yz loads while wave 0 reduces
    float smv[M];
#pragma unroll
    for (int m = 0; m < M; ++m) smv[m] = ws[OFF_S + m];   // uniform -> s_load
    float4 a4[M];
    const float* yp = ws + OFF_YZW + (size_t)b * M * HW + hw;
#pragma unroll
    for (int m = 0; m < M; ++m)
        a4[m] = *reinterpret_cast<const float4*>(yp + (size_t)m * HW);
    __syncthreads();
    const float mu = sh[0], istd = sh[1];

    float4 y4[M];
#pragma unroll
    for (int m = 0; m < M; ++m) {
        float off = mu * smv[m];
        y4[m].x = istd * (a4[m].x - off);
        y4[m].y = istd * (a4[m].y - off);
        y4[m].z = istd * (a4[m].z - off);
        y4[m].w = istd * (a4[m].w - off);
    }

    const float* zp = z + ((size_t)(b * C + c0)) * HW + hw;
    float* op = out + ((size_t)(b * C + c0)) * HW + hw;
#pragma unroll 8
    for (int ci = 0; ci < 32; ++ci) {
        float4 v = *reinterpret_cast<const float4*>(zp + (size_t)ci * HW);
        const int c = c0 + ci;
        float r0 = 0.f, r1 = 0.f, r2 = 0.f, r3 = 0.f;
#pragma unroll
        for (int m = 0; m < M; ++m) {
            float w = Wd[m * C + c];           // wave-uniform -> s_load
            r0 += w * y4[m].x; r1 += w * y4[m].y;
            r2 += w * y4[m].z; r3 += w * y4[m].w;
        }
        floatx4 o;
        o.x = v.x + GAIN * r0; o.y = v.y + GAIN * r1;
        o.z = v.z + GAIN * r2; o.w = v.w + GAIN * r3;
        __builtin_nontemporal_store(o, reinterpret_cast<floatx4*>(op + (size_t)ci * HW));
    }
}

extern "C" void kernel_launch(void* const* d_in, const int* in_sizes, int n_in,
                              void* d_out, int out_size, void* d_ws, size_t ws_size,
                              hipStream_t stream) {
    const float* z  = (const float*)d_in[0];   // (8,1024,64,64) fp32
    const float* Wd = (const float*)d_in[1];   // (8,1024) fp32
    float* out = (float*)d_out;
    float* ws  = (float*)d_ws;                 // ~1.05 MB

    k1_stats_yz<<<dim3(512), dim3(512), 0, stream>>>(z, Wd, ws);
    k3_apply<<<dim3(1024), dim3(256), 0, stream>>>(z, Wd, ws, out);
}